// Round 6
// baseline (168.426 us; speedup 1.0000x reference)
//
#include <hip/hip_runtime.h>
#include <math.h>

// B=4, T=512, IDIM=128, HDIM=1024, CDIM=256
#define NROWS 2048
#define NBLK  2048            // one row per block, 4 waves per block
#define NITER 4
#define IGNORE_OUT 10000.0f

__device__ __forceinline__ float readlanef(float v, int lane){
  return __int_as_float(__builtin_amdgcn_readlane(__float_as_int(v), lane));
}
// lane l receives lane (l-1)&63  (wavefront rotate by 1)
__device__ __forceinline__ float rotup1(float v){
  int i = __float_as_int(v);
  return __int_as_float(__builtin_amdgcn_update_dpp(i, i, 0x13C, 0xF, 0xF, false));
}
// gather from 128-vector held as two regs; 0 outside [0,128)
__device__ __forceinline__ float gather128(float v0, float v1, int idx){
  float g0 = __shfl(v0, idx & 63, 64);
  float g1 = __shfl(v1, idx & 63, 64);
  float r  = (idx & 64) ? g1 : g0;
  return ((unsigned)idx < 128u) ? r : 0.f;
}
__device__ __forceinline__ float bflySum(float v){
  #pragma unroll
  for (int o = 32; o; o >>= 1) v += __shfl_xor(v, o, 64);
  return v;
}

// ---------- prep kernel ----------
// blocks 0..511 : G[d][o] = sum_c w1[c,d]*w2[o,c], quad-packed:
//   M4[i][dd][o] = float4(G[4dd..4dd+3][o]); float index i*16384 + dd*512 + o*4 + e
// blocks 512..515 : biasT[i][o] = b2[o] + sum_c b1[c]*w2[o,c]
// block 516 : zero the ticket
__global__ __launch_bounds__(128)
void prepK(const float* __restrict__ w1, const float* __restrict__ b1,
           const float* __restrict__ w2, const float* __restrict__ b2,
           float* __restrict__ M4, float* __restrict__ biasT, int* __restrict__ ticket){
  const int blk = blockIdx.x;
  const int u = threadIdx.x;
  if (blk < 512){
    int i = blk >> 7, o = blk & 127;
    const float* w1p = w1 + (i * 256) * 128 + u;   // coalesced over d=u
    const float* w2p = w2 + o * 1024 + i * 256;    // thread-uniform
    float a = 0.f;
    #pragma unroll 16
    for (int c = 0; c < 256; ++c) a = fmaf(w1p[c * 128], w2p[c], a);
    M4[i * 16384 + (u >> 2) * 512 + o * 4 + (u & 3)] = a;
  } else if (blk < 516){
    int i = blk - 512;
    const float* w2p = w2 + u * 1024 + i * 256;
    const float* b1p = b1 + i * 256;
    float a = b2[u];
    #pragma unroll 8
    for (int c = 0; c < 256; ++c) a = fmaf(b1p[c], w2p[c], a);
    biasT[i * 128 + u] = a;
  } else {
    if (u == 0) *ticket = 0;
  }
}

// ---------- main kernel: one row per block, 4 waves split (shift-group × j-range) ----------
// wave w: shift group g = w&1 (pairs t = 64g + l), j-range half = w>>1 (j in [64h, 64h+64))
__global__ __launch_bounds__(256, 8)
void mainK(const float* __restrict__ x, const float* __restrict__ y,
           const float* __restrict__ M4, const float* __restrict__ biasT,
           unsigned long long* __restrict__ partials, int* __restrict__ ticket,
           float* __restrict__ out){
  __shared__ float pNT[256];
  __shared__ float pN1[256];
  __shared__ float yel[128];
  __shared__ float sVal[2];
  __shared__ int   sIdx[2];
  __shared__ float sL[4], sC[4];
  __shared__ int   sOld;

  const int u = threadIdx.x;               // 0..255
  const int l = u & 63;
  const int w = u >> 6;                    // wave 0..3
  const bool isl0 = (l == 0);
  const long base = (long)blockIdx.x * 128;

  // every wave holds the FULL row in registers (2+2 regs)
  float xlo = x[base + l], xhi = x[base + 64 + l];
  float ylo = y[base + l], yhi = y[base + 64 + l];
  const bool mlo = (ylo == IGNORE_OUT), mhi = (yhi == IGNORE_OUT);
  const bool mOwn = (w == 0) ? mlo : mhi;  // thread u<128 owns element o=u
  float cnt = (u < 128 && !mOwn) ? 1.f : 0.f;
  float lossAcc = 0.f;

  for (int i = 0; i < NITER; ++i){
    // ---- window-norm prefix + ||y|| (waves 0,1 only; register scans) ----
    float pref_t = 0.f, total = 0.f, nY = 0.f;
    if (w < 2){
      float own2 = (w == 0) ? xlo * xlo : xhi * xhi;
      float oth2 = (w == 0) ? xhi * xhi : xlo * xlo;
      float v = own2;
      #pragma unroll
      for (int o2 = 1; o2 < 64; o2 <<= 1){
        float tv = __shfl_up(v, o2, 64);
        if (l >= o2) v += tv;
      }
      float osum = bflySum(oth2);
      pref_t = (w == 0) ? v : (v + osum);      // inclusive prefix at t = 64w + l
      total  = readlanef(v, 63) + osum;
      nY = sqrtf(bflySum(ylo * ylo + yhi * yhi));
    }

    // ---- corr: 64 register-rotation steps per wave ----
    // window win(t, J)[lane=l] = y[(127 - 64g - l + J) % 128], J = 64h + j
    // init: waves 0,3 -> yhi[63-l]; waves 1,2 -> ylo[63-l]
    // lane0 incoming at local step j: waves 0,3 -> ylo[j]; waves 1,2 -> yhi[j]
    // sx = x[J]: waves 0,1 -> xlo[j]; waves 2,3 -> xhi[j]
    {
      const bool a03 = (w == 0) || (w == 3);
      float winsrc = a03 ? yhi : ylo;
      float incSrc = a03 ? ylo : yhi;
      float sxSrc  = (w < 2) ? xlo : xhi;
      float win = __shfl(winsrc, 63 - l, 64);
      float nt = 0.f, n1 = 0.f;
      if (a03){                              // snap waves: j==l boundary in range
        #pragma unroll 8
        for (int j = 0; j < 64; ++j){
          float sx = readlanef(sxSrc, j);
          nt = fmaf(win, sx, nt);
          n1 = (j == l) ? nt : n1;
          float inc = readlanef(incSrc, j);
          float r = rotup1(win);
          win = isl0 ? inc : r;
        }
      } else {
        #pragma unroll 8
        for (int j = 0; j < 64; ++j){
          float sx = readlanef(sxSrc, j);
          nt = fmaf(win, sx, nt);
          float inc = readlanef(incSrc, j);
          float r = rotup1(win);
          win = isl0 ? inc : r;
        }
        if (w == 1) n1 = nt;                 // all j in [0,64) are <= t = 64+l
        // w == 2: j in [64,128) all > t = l -> n1 = 0
      }
      pNT[u] = nt; pN1[u] = n1;
    }
    __syncthreads();                         // B1

    // ---- sims + per-wave argmax (u < 128); pair t=u -> shifts {t, t+128} ----
    if (w < 2){
      float numt = pNT[u] + pNT[u + 128];
      float num1 = pN1[u] + pN1[u + 128];
      float num2 = numt - num1;
      float d1 = nY * sqrtf(pref_t);
      float d2 = nY * sqrtf(fmaxf(total - pref_t, 0.f));
      float s1 = (d1 == 0.f) ? 0.f : num1 / d1;
      float s2 = (d2 == 0.f) ? 0.f : num2 / d2;
      if (u == 127) s2 = -INFINITY;          // shift 255 doesn't exist
      float bv = s1; int bi = u;
      if (s2 > bv){ bv = s2; bi = u + 128; }
      #pragma unroll
      for (int o2 = 1; o2 < 64; o2 <<= 1){
        float ov = __shfl_xor(bv, o2, 64);
        int   oi = __shfl_xor(bi, o2, 64);
        if (ov > bv || (ov == bv && oi < bi)){ bv = ov; bi = oi; }
      }
      if (l == 0){ sVal[w] = bv; sIdx[w] = bi; }
    }
    __syncthreads();                         // B2
    int sstar;
    {
      float v0 = sVal[0], v1 = sVal[1];
      int   i0 = sIdx[0], i1 = sIdx[1];
      sstar = (v1 > v0 || (v1 == v0 && i1 < i0)) ? i1 : i0;
    }

    // ---- x_aug + detached softmax (all waves; no max-subtract: |z| << 88) ----
    int j0 = sstar + l - 127;
    float xa = gather128(xlo, xhi, j0);
    float xb = gather128(xlo, xhi, j0 + 64);
    float ea = expf(xa * ylo), eb = expf(xb * yhi);
    float se = bflySum(ea + eb);
    float wlo = xa * (ea / se), whi = xb * (eb / se);   // xatt

    // ---- x_res update (reverse shift) ----
    int k0 = l + 127 - sstar;
    xlo -= gather128(wlo, whi, k0);
    xhi -= gather128(wlo, whi, k0 + 64);

    // ---- MLP: thread u -> output o = u&127, d-half h = u>>7 (16 b128 loads) ----
    {
      const float4* Mp = (const float4*)(M4 + (size_t)i * 16384);
      float src = (u < 128) ? wlo : whi;     // d<64 -> wlo ; d>=64 -> whi
      int o = u & 127;
      int qb = (u >> 7) * 16;
      float av = 0.f;
      #pragma unroll
      for (int q = 0; q < 16; ++q){
        float4 m = Mp[(qb + q) * 128 + o];
        av = fmaf(m.x, readlanef(src, 4 * q + 0), av);
        av = fmaf(m.y, readlanef(src, 4 * q + 1), av);
        av = fmaf(m.z, readlanef(src, 4 * q + 2), av);
        av = fmaf(m.w, readlanef(src, 4 * q + 3), av);
      }
      pNT[u] = av;                           // reuse as MLP partials (old reads done pre-B2)
    }
    __syncthreads();                         // B3
    if (u < 128){
      float ye = pNT[u] + pNT[u + 128] + biasT[i * 128 + u];
      float yo = (w == 0) ? ylo : yhi;
      float df = ye - yo;
      if (!mOwn) lossAcc = fmaf(df, df, lossAcc);
      yel[u] = ye;
    }
    __syncthreads();                         // B4
    ylo = -(yel[l] - ylo);                   // y_res -= y_ele
    yhi = -(yel[64 + l] - yhi);
  }

  // ---- block loss/cnt, partial store + ticket; last block finalizes ----
  lossAcc = bflySum(lossAcc);
  cnt     = bflySum(cnt);
  if (l == 0){ sL[w] = lossAcc; sC[w] = cnt; }
  __syncthreads();
  if (u == 0){
    union { float2 f; unsigned long long v; } pk;
    pk.f.x = sL[0] + sL[1] + sL[2] + sL[3];
    pk.f.y = sC[0] + sC[1] + sC[2] + sC[3];
    __hip_atomic_store(&partials[blockIdx.x], pk.v, __ATOMIC_RELEASE, __HIP_MEMORY_SCOPE_AGENT);
    sOld = __hip_atomic_fetch_add(ticket, 1, __ATOMIC_ACQ_REL, __HIP_MEMORY_SCOPE_AGENT);
  }
  __syncthreads();
  if (sOld == NBLK - 1){
    float ls = 0.f, cs = 0.f;
    for (int g = u; g < NBLK; g += 256){
      union { float2 f; unsigned long long v; } pk;
      pk.v = __hip_atomic_load(&partials[g], __ATOMIC_ACQUIRE, __HIP_MEMORY_SCOPE_AGENT);
      ls += pk.f.x; cs += pk.f.y;
    }
    ls = bflySum(ls); cs = bflySum(cs);
    if (l == 0){ sL[w] = ls; sC[w] = cs; }
    __syncthreads();
    if (u == 0)
      out[0] = (sL[0] + sL[1] + sL[2] + sL[3]) /
               ((float)NITER * (sC[0] + sC[1] + sC[2] + sC[3]));
  }
}

extern "C" void kernel_launch(void* const* d_in, const int* in_sizes, int n_in,
                              void* d_out, int out_size, void* d_ws, size_t ws_size,
                              hipStream_t stream){
  const float* x  = (const float*)d_in[0];
  const float* y  = (const float*)d_in[1];
  const float* w1 = (const float*)d_in[2];
  const float* b1 = (const float*)d_in[3];
  const float* w2 = (const float*)d_in[4];
  const float* b2 = (const float*)d_in[5];
  float* out = (float*)d_out;

  // ws: [0,4) ticket ; [256, 256+256K) M4 ; +2K biasT ; +16K partials
  int*   ticket = (int*)d_ws;
  float* M4     = (float*)((char*)d_ws + 256);
  float* biasT  = (float*)((char*)d_ws + 256 + 4 * 128 * 128 * sizeof(float));
  unsigned long long* partials =
      (unsigned long long*)((char*)d_ws + 256 + 4 * 128 * 128 * sizeof(float) + 4 * 128 * sizeof(float));

  prepK<<<517, 128, 0, stream>>>(w1, b1, w2, b2, M4, biasT, ticket);
  mainK<<<NBLK, 256, 0, stream>>>(x, y, M4, biasT, partials, ticket, out);
}

// Round 7
// 164.826 us; speedup vs baseline: 1.0218x; 1.0218x over previous
//
#include <hip/hip_runtime.h>
#include <math.h>

// B=4, T=512, IDIM=128, HDIM=1024, CDIM=256
#define NROWS 2048
#define NBLK  2048            // one row per block, 4 waves per block
#define NITER 4
#define IGNORE_OUT 10000.0f

__device__ __forceinline__ float readlanef(float v, int lane){
  return __int_as_float(__builtin_amdgcn_readlane(__float_as_int(v), lane));
}
// gather from 128-vector held as two regs; 0 outside [0,128)
__device__ __forceinline__ float gather128(float v0, float v1, int idx){
  float g0 = __shfl(v0, idx & 63, 64);
  float g1 = __shfl(v1, idx & 63, 64);
  float r  = (idx & 64) ? g1 : g0;
  return ((unsigned)idx < 128u) ? r : 0.f;
}
__device__ __forceinline__ float bflySum(float v){
  #pragma unroll
  for (int o = 32; o; o >>= 1) v += __shfl_xor(v, o, 64);
  return v;
}

// ---------- prep kernel (unchanged from r6) ----------
// blocks 0..511 : G[d][o] = sum_c w1[c,d]*w2[o,c], quad-packed:
//   M4[i][dd][o] = float4(G[4dd..4dd+3][o]); float index i*16384 + dd*512 + o*4 + e
// blocks 512..515 : biasT[i][o] = b2[o] + sum_c b1[c]*w2[o,c]
// block 516 : zero the ticket
__global__ __launch_bounds__(128)
void prepK(const float* __restrict__ w1, const float* __restrict__ b1,
           const float* __restrict__ w2, const float* __restrict__ b2,
           float* __restrict__ M4, float* __restrict__ biasT, int* __restrict__ ticket){
  const int blk = blockIdx.x;
  const int u = threadIdx.x;
  if (blk < 512){
    int i = blk >> 7, o = blk & 127;
    const float* w1p = w1 + (i * 256) * 128 + u;   // coalesced over d=u
    const float* w2p = w2 + o * 1024 + i * 256;    // thread-uniform
    float a = 0.f;
    #pragma unroll 16
    for (int c = 0; c < 256; ++c) a = fmaf(w1p[c * 128], w2p[c], a);
    M4[i * 16384 + (u >> 2) * 512 + o * 4 + (u & 3)] = a;
  } else if (blk < 516){
    int i = blk - 512;
    const float* w2p = w2 + u * 1024 + i * 256;
    const float* b1p = b1 + i * 256;
    float a = b2[u];
    #pragma unroll 8
    for (int c = 0; c < 256; ++c) a = fmaf(b1p[c], w2p[c], a);
    biasT[i * 128 + u] = a;
  } else {
    if (u == 0) *ticket = 0;
  }
}

// ---------- main kernel: one row per block, 4 waves; LDS-window correlation ----------
// wave w: shift group g=w&1 (pairs t = 64g + l), j-half h=w>>1 (J = 64h + j)
// window value = y[(127 - 64g + 64h - l + j) % 128] = yd[(127 - 64g + 64h - l) + j]
__global__ __launch_bounds__(256, 8)
void mainK(const float* __restrict__ x, const float* __restrict__ y,
           const float* __restrict__ M4, const float* __restrict__ biasT,
           unsigned long long* __restrict__ partials, int* __restrict__ ticket,
           float* __restrict__ out){
  __shared__ float pNT[256];
  __shared__ float pN1[256];
  __shared__ float yd[256];     // yd[m] = y_res[m & 127]
  __shared__ float sVal[2];
  __shared__ int   sIdx[2];
  __shared__ float sL[4], sC[4];
  __shared__ int   sOld;

  const int u = threadIdx.x;               // 0..255
  const int l = u & 63;
  const int w = u >> 6;                    // wave 0..3
  const long base = (long)blockIdx.x * 128;

  // every wave holds the FULL row in registers
  float xlo = x[base + l], xhi = x[base + 64 + l];
  float ylo = y[base + l], yhi = y[base + 64 + l];
  const bool mOwn = (u < 128) && (((w == 0) ? ylo : yhi) == IGNORE_OUT);
  float cnt = (u < 128 && !mOwn) ? 1.f : 0.f;
  float lossAcc = 0.f;

  if (u < 128){                            // thread u owns element u
    float yOwn = (w == 0) ? ylo : yhi;
    yd[u] = yOwn; yd[128 + u] = yOwn;
  }
  __syncthreads();

  for (int i = 0; i < NITER; ++i){
    // ---- corr: 64 steps; window from LDS (1 ds_read_b32 each, imm offsets) ----
    {
      const int g = w & 1, h = w >> 1;
      const float* wp = yd + (127 - 64 * g + 64 * h - l);   // in [0,191]
      float sxSrc = h ? xhi : xlo;         // x[J], J = 64h + j
      float nt = 0.f, n1 = 0.f;
      if (w == 0 || w == 3){               // snap waves: boundary J==t at j==l
        #pragma unroll
        for (int j = 0; j < 64; ++j){
          float win = wp[j];
          nt = fmaf(win, readlanef(sxSrc, j), nt);
          n1 = (j == l) ? nt : n1;
        }
      } else {
        #pragma unroll
        for (int j = 0; j < 64; ++j){
          float win = wp[j];
          nt = fmaf(win, readlanef(sxSrc, j), nt);
        }
        if (w == 1) n1 = nt;               // w1: all its J <= t ; w2: none (n1=0)
      }
      pNT[u] = nt; pN1[u] = n1;
    }
    __syncthreads();                       // B1

    // ---- scans + sims + argmax on the LIGHT corr waves (1,2) ----
    if (w == 1 || w == 2){
      float own2 = (w == 1) ? xlo * xlo : xhi * xhi;
      float oth2 = (w == 1) ? xhi * xhi : xlo * xlo;
      float v = own2;
      #pragma unroll
      for (int o2 = 1; o2 < 64; o2 <<= 1){
        float tv = __shfl_up(v, o2, 64);
        if (l >= o2) v += tv;
      }
      float osum   = bflySum(oth2);
      float total  = readlanef(v, 63) + osum;
      float pref_t = (w == 1) ? v : (v + osum);   // prefix at t = (w-1)*64 + l
      float nY = sqrtf(bflySum(ylo * ylo + yhi * yhi));
      int t = (w == 1) ? l : (64 + l);
      float numt = pNT[t] + pNT[t + 128];
      float num1 = pN1[t] + pN1[t + 128];
      float num2 = numt - num1;
      float d1 = nY * sqrtf(pref_t);
      float d2 = nY * sqrtf(fmaxf(total - pref_t, 0.f));
      float s1 = (d1 == 0.f) ? 0.f : num1 / d1;
      float s2 = (d2 == 0.f) ? 0.f : num2 / d2;
      if (t == 127) s2 = -INFINITY;        // shift 255 doesn't exist
      float bv = s1; int bi = t;
      if (s2 > bv){ bv = s2; bi = t + 128; }
      #pragma unroll
      for (int o2 = 1; o2 < 64; o2 <<= 1){
        float ov = __shfl_xor(bv, o2, 64);
        int   oi = __shfl_xor(bi, o2, 64);
        if (ov > bv || (ov == bv && oi < bi)){ bv = ov; bi = oi; }
      }
      if (l == 0){ sVal[w - 1] = bv; sIdx[w - 1] = bi; }
    }
    __syncthreads();                       // B2
    int sstar;
    {
      float v0 = sVal[0], v1 = sVal[1];
      int   i0 = sIdx[0], i1 = sIdx[1];
      sstar = (v1 > v0 || (v1 == v0 && i1 < i0)) ? i1 : i0;
    }

    // ---- x_aug + detached softmax (all waves; |z| << 88 so no max-subtract) ----
    int j0 = sstar + l - 127;
    float xa = gather128(xlo, xhi, j0);
    float xb = gather128(xlo, xhi, j0 + 64);
    float ea = expf(xa * ylo), eb = expf(xb * yhi);
    float se = bflySum(ea + eb);
    float wlo = xa * (ea / se), whi = xb * (eb / se);   // xatt

    // ---- x_res update (reverse shift) ----
    int k0 = l + 127 - sstar;
    xlo -= gather128(wlo, whi, k0);
    xhi -= gather128(wlo, whi, k0 + 64);

    // ---- MLP: thread u -> output o = u&127, d-half = u>>7 (16 b128 VMEM) ----
    {
      const float4* Mp = (const float4*)(M4 + (size_t)i * 16384);
      float src = (u < 128) ? wlo : whi;   // d<64 -> wlo ; d>=64 -> whi
      int o = u & 127;
      int qb = (u >> 7) * 16;
      float av = 0.f;
      #pragma unroll
      for (int q = 0; q < 16; ++q){
        float4 m = Mp[(qb + q) * 128 + o];
        av = fmaf(m.x, readlanef(src, 4 * q + 0), av);
        av = fmaf(m.y, readlanef(src, 4 * q + 1), av);
        av = fmaf(m.z, readlanef(src, 4 * q + 2), av);
        av = fmaf(m.w, readlanef(src, 4 * q + 3), av);
      }
      pNT[u] = av;                         // reuse as MLP partials (sims done pre-B2)
    }
    __syncthreads();                       // B3
    if (u < 128){
      float ye = pNT[u] + pNT[u + 128] + biasT[i * 128 + u];
      float yOwn = (w == 0) ? ylo : yhi;
      float df = ye - yOwn;
      if (!mOwn) lossAcc = fmaf(df, df, lossAcc);
      float yNew = yOwn - ye;              // y_res -= y_ele
      yd[u] = yNew; yd[128 + u] = yNew;
    }
    __syncthreads();                       // B4
    ylo = yd[l]; yhi = yd[64 + l];         // refresh register copies
  }

  // ---- block loss/cnt, partial store + ticket; last block finalizes ----
  lossAcc = bflySum(lossAcc);
  cnt     = bflySum(cnt);
  if (l == 0){ sL[w] = lossAcc; sC[w] = cnt; }
  __syncthreads();
  if (u == 0){
    union { float2 f; unsigned long long v; } pk;
    pk.f.x = sL[0] + sL[1] + sL[2] + sL[3];
    pk.f.y = sC[0] + sC[1] + sC[2] + sC[3];
    __hip_atomic_store(&partials[blockIdx.x], pk.v, __ATOMIC_RELEASE, __HIP_MEMORY_SCOPE_AGENT);
    sOld = __hip_atomic_fetch_add(ticket, 1, __ATOMIC_ACQ_REL, __HIP_MEMORY_SCOPE_AGENT);
  }
  __syncthreads();
  if (sOld == NBLK - 1){
    float ls = 0.f, cs = 0.f;
    for (int gg = u; gg < NBLK; gg += 256){
      union { float2 f; unsigned long long v; } pk;
      pk.v = __hip_atomic_load(&partials[gg], __ATOMIC_ACQUIRE, __HIP_MEMORY_SCOPE_AGENT);
      ls += pk.f.x; cs += pk.f.y;
    }
    ls = bflySum(ls); cs = bflySum(cs);
    if (l == 0){ sL[w] = ls; sC[w] = cs; }
    __syncthreads();
    if (u == 0)
      out[0] = (sL[0] + sL[1] + sL[2] + sL[3]) /
               ((float)NITER * (sC[0] + sC[1] + sC[2] + sC[3]));
  }
}

extern "C" void kernel_launch(void* const* d_in, const int* in_sizes, int n_in,
                              void* d_out, int out_size, void* d_ws, size_t ws_size,
                              hipStream_t stream){
  const float* x  = (const float*)d_in[0];
  const float* y  = (const float*)d_in[1];
  const float* w1 = (const float*)d_in[2];
  const float* b1 = (const float*)d_in[3];
  const float* w2 = (const float*)d_in[4];
  const float* b2 = (const float*)d_in[5];
  float* out = (float*)d_out;

  // ws: [0,4) ticket ; [256, 256+256K) M4 ; +2K biasT ; +16K partials
  int*   ticket = (int*)d_ws;
  float* M4     = (float*)((char*)d_ws + 256);
  float* biasT  = (float*)((char*)d_ws + 256 + 4 * 128 * 128 * sizeof(float));
  unsigned long long* partials =
      (unsigned long long*)((char*)d_ws + 256 + 4 * 128 * 128 * sizeof(float) + 4 * 128 * sizeof(float));

  prepK<<<517, 128, 0, stream>>>(w1, b1, w2, b2, M4, biasT, ticket);
  mainK<<<NBLK, 256, 0, stream>>>(x, y, M4, biasT, partials, ticket, out);
}

// Round 8
// 159.758 us; speedup vs baseline: 1.0543x; 1.0317x over previous
//
#include <hip/hip_runtime.h>
#include <math.h>

// B=4, T=512, IDIM=128, HDIM=1024, CDIM=256
#define NROWS 2048
#define NBLK  2048            // one row per block, 2 waves per block
#define NITER 4
#define IGNORE_OUT 10000.0f

__device__ __forceinline__ float readlanef(float v, int lane){
  return __int_as_float(__builtin_amdgcn_readlane(__float_as_int(v), lane));
}
// gather from 128-vector held as two regs; 0 outside [0,128)
__device__ __forceinline__ float gather128(float v0, float v1, int idx){
  float g0 = __shfl(v0, idx & 63, 64);
  float g1 = __shfl(v1, idx & 63, 64);
  float r  = (idx & 64) ? g1 : g0;
  return ((unsigned)idx < 128u) ? r : 0.f;
}
__device__ __forceinline__ float bflySum(float v){
  #pragma unroll
  for (int o = 32; o; o >>= 1) v += __shfl_xor(v, o, 64);
  return v;
}

// ---------- prep kernel (r7 layout) ----------
// blocks 0..511 : G[d][o] = sum_c w1[c,d]*w2[o,c], quad-packed:
//   M4[i][dd][o] = float4(G[4dd..4dd+3][o]); float index i*16384 + dd*512 + o*4 + e
// blocks 512..515 : biasT[i][o] = b2[o] + sum_c b1[c]*w2[o,c]
// block 516 : zero the ticket
__global__ __launch_bounds__(128)
void prepK(const float* __restrict__ w1, const float* __restrict__ b1,
           const float* __restrict__ w2, const float* __restrict__ b2,
           float* __restrict__ M4, float* __restrict__ biasT, int* __restrict__ ticket){
  const int blk = blockIdx.x;
  const int u = threadIdx.x;
  if (blk < 512){
    int i = blk >> 7, o = blk & 127;
    const float* w1p = w1 + (i * 256) * 128 + u;   // coalesced over d=u
    const float* w2p = w2 + o * 1024 + i * 256;    // thread-uniform
    float a = 0.f;
    #pragma unroll 16
    for (int c = 0; c < 256; ++c) a = fmaf(w1p[c * 128], w2p[c], a);
    M4[i * 16384 + (u >> 2) * 512 + o * 4 + (u & 3)] = a;
  } else if (blk < 516){
    int i = blk - 512;
    const float* w2p = w2 + u * 1024 + i * 256;
    const float* b1p = b1 + i * 256;
    float a = b2[u];
    #pragma unroll 8
    for (int c = 0; c < 256; ++c) a = fmaf(b1p[c], w2p[c], a);
    biasT[i * 128 + u] = a;
  } else {
    if (u == 0) *ticket = 0;
  }
}

// ---------- main kernel: one row per block, 2 waves; LDS-window corr, min ops ----------
// wave w handles shift-pair t = 64w + l (shifts t and t+128), full j range [0,128)
// window value for (t, j) = y[(255 - t + j) % 128] = yd[(255 - t) + j], yd[384] duplicated
__global__ __launch_bounds__(128, 4)
void mainK(const float* __restrict__ x, const float* __restrict__ y,
           const float* __restrict__ M4, const float* __restrict__ biasT,
           unsigned long long* __restrict__ partials, int* __restrict__ ticket,
           float* __restrict__ out){
  __shared__ float yd[384];     // yd[128+k] = yd[256+k] = y_res[k]
  __shared__ float yel[128];
  __shared__ float sVal[2];
  __shared__ int   sIdx[2];
  __shared__ float sL[2], sC[2];
  __shared__ int   sOld;

  const int u = threadIdx.x;               // 0..127 ; u = 64w + l = owned element / MLP output
  const int l = u & 63;
  const int w = u >> 6;
  const long base = (long)blockIdx.x * 128;

  // both waves hold the FULL row in registers
  float xlo = x[base + l], xhi = x[base + 64 + l];
  float ylo = y[base + l], yhi = y[base + 64 + l];
  const float yOwn0 = w ? yhi : ylo;       // element u (original y)
  const bool mOwn = (yOwn0 == IGNORE_OUT);
  float cnt = mOwn ? 0.f : 1.f;
  float lossAcc = 0.f;

  yd[128 + u] = yOwn0; yd[256 + u] = yOwn0;
  __syncthreads();

  for (int i = 0; i < NITER; ++i){
    // ---- window-norm prefix at t = 64w+l (each wave scans its own half) ----
    float own2 = w ? xhi * xhi : xlo * xlo;
    float oth2 = w ? xlo * xlo : xhi * xhi;
    float v = own2;
    #pragma unroll
    for (int o2 = 1; o2 < 64; o2 <<= 1){
      float tv = __shfl_up(v, o2, 64);
      if (l >= o2) v += tv;
    }
    float osum   = bflySum(oth2);
    float total  = readlanef(v, 63) + osum;
    float pref_t = w ? (v + osum) : v;     // inclusive prefix of x^2 at index t

    // ---- ||y_res|| ----
    float nY = sqrtf(bflySum(ylo * ylo + yhi * yhi));

    // ---- corr: 128 LDS-window steps; snap at j==t gives num(shift t) ----
    const float* wp = yd + (255 - u);      // base in [128, 255]
    float nt = 0.f, n1 = 0.f;
    if (w == 0){                           // t = l: snap in first half
      #pragma unroll 8
      for (int j = 0; j < 64; ++j){
        nt = fmaf(wp[j], readlanef(xlo, j), nt);
        n1 = (j == l) ? nt : n1;
      }
      #pragma unroll 8
      for (int j = 0; j < 64; ++j)
        nt = fmaf(wp[64 + j], readlanef(xhi, j), nt);
    } else {                               // t = 64+l: first half all j<=t
      #pragma unroll 8
      for (int j = 0; j < 64; ++j)
        nt = fmaf(wp[j], readlanef(xlo, j), nt);
      n1 = nt;
      #pragma unroll 8
      for (int j = 0; j < 64; ++j){
        nt = fmaf(wp[64 + j], readlanef(xhi, j), nt);
        n1 = (j == l) ? nt : n1;
      }
    }

    // ---- cosine sims for shifts {t, t+128}; wave argmax; cross-wave combine ----
    {
      float num2 = nt - n1;
      float d1 = nY * sqrtf(pref_t);
      float d2 = nY * sqrtf(fmaxf(total - pref_t, 0.f));
      float s1 = (d1 == 0.f) ? 0.f : n1 / d1;
      float s2 = (d2 == 0.f) ? 0.f : num2 / d2;
      if (u == 127) s2 = -INFINITY;        // shift 255 doesn't exist
      float bv = s1; int bi = u;
      if (s2 > bv){ bv = s2; bi = u + 128; }
      #pragma unroll
      for (int o2 = 1; o2 < 64; o2 <<= 1){
        float ov = __shfl_xor(bv, o2, 64);
        int   oi = __shfl_xor(bi, o2, 64);
        if (ov > bv || (ov == bv && oi < bi)){ bv = ov; bi = oi; }
      }
      if (l == 0){ sVal[w] = bv; sIdx[w] = bi; }
    }
    __syncthreads();                       // B1
    int sstar;
    {
      float v0 = sVal[0], v1 = sVal[1];
      int   i0 = sIdx[0], i1 = sIdx[1];
      sstar = (v1 > v0 || (v1 == v0 && i1 < i0)) ? i1 : i0;
    }

    // ---- x_aug + detached softmax (|z| << 88 so no max-subtract; verified r7) ----
    int j0 = sstar + l - 127;
    float xa = gather128(xlo, xhi, j0);
    float xb = gather128(xlo, xhi, j0 + 64);
    float ea = expf(xa * ylo), eb = expf(xb * yhi);
    float se = bflySum(ea + eb);
    float wlo = xa * (ea / se), whi = xb * (eb / se);   // xatt

    // ---- x_res update (reverse shift) ----
    int k0 = l + 127 - sstar;
    xlo -= gather128(wlo, whi, k0);
    xhi -= gather128(wlo, whi, k0 + 64);

    // ---- MLP: thread u -> output o = u; 32 coalesced b128 loads ----
    float ye;
    {
      const float4* Mp = (const float4*)(M4 + (size_t)i * 16384);
      float av = 0.f;
      #pragma unroll 4
      for (int dd = 0; dd < 16; ++dd){
        float4 m = Mp[dd * 128 + u];
        av = fmaf(m.x, readlanef(wlo, 4 * dd + 0), av);
        av = fmaf(m.y, readlanef(wlo, 4 * dd + 1), av);
        av = fmaf(m.z, readlanef(wlo, 4 * dd + 2), av);
        av = fmaf(m.w, readlanef(wlo, 4 * dd + 3), av);
      }
      #pragma unroll 4
      for (int dd = 16; dd < 32; ++dd){
        float4 m = Mp[dd * 128 + u];
        int b = 4 * dd - 64;
        av = fmaf(m.x, readlanef(whi, b + 0), av);
        av = fmaf(m.y, readlanef(whi, b + 1), av);
        av = fmaf(m.z, readlanef(whi, b + 2), av);
        av = fmaf(m.w, readlanef(whi, b + 3), av);
      }
      ye = av + biasT[i * 128 + u];
    }

    // ---- loss on owned element + publish y_ele / new y_res ----
    {
      float yOwn = w ? yhi : ylo;          // current y_res[u]
      float df = ye - yOwn;
      if (!mOwn) lossAcc = fmaf(df, df, lossAcc);
      float yNew = yOwn - ye;
      yel[u] = ye;
      yd[128 + u] = yNew; yd[256 + u] = yNew;
    }
    __syncthreads();                       // B2
    ylo = ylo - yel[l];                    // refresh register copies
    yhi = yhi - yel[64 + l];
  }

  // ---- block loss/cnt, partial store + ticket; last block finalizes ----
  lossAcc = bflySum(lossAcc);
  cnt     = bflySum(cnt);
  if (l == 0){ sL[w] = lossAcc; sC[w] = cnt; }
  __syncthreads();
  if (u == 0){
    union { float2 f; unsigned long long v; } pk;
    pk.f.x = sL[0] + sL[1];
    pk.f.y = sC[0] + sC[1];
    __hip_atomic_store(&partials[blockIdx.x], pk.v, __ATOMIC_RELEASE, __HIP_MEMORY_SCOPE_AGENT);
    sOld = __hip_atomic_fetch_add(ticket, 1, __ATOMIC_ACQ_REL, __HIP_MEMORY_SCOPE_AGENT);
  }
  __syncthreads();
  if (sOld == NBLK - 1){
    float ls = 0.f, cs = 0.f;
    for (int g = u; g < NBLK; g += 128){
      union { float2 f; unsigned long long v; } pk;
      pk.v = __hip_atomic_load(&partials[g], __ATOMIC_ACQUIRE, __HIP_MEMORY_SCOPE_AGENT);
      ls += pk.f.x; cs += pk.f.y;
    }
    ls = bflySum(ls); cs = bflySum(cs);
    if (l == 0){ sL[w] = ls; sC[w] = cs; }
    __syncthreads();
    if (u == 0) out[0] = (sL[0] + sL[1]) / ((float)NITER * (sC[0] + sC[1]));
  }
}

extern "C" void kernel_launch(void* const* d_in, const int* in_sizes, int n_in,
                              void* d_out, int out_size, void* d_ws, size_t ws_size,
                              hipStream_t stream){
  const float* x  = (const float*)d_in[0];
  const float* y  = (const float*)d_in[1];
  const float* w1 = (const float*)d_in[2];
  const float* b1 = (const float*)d_in[3];
  const float* w2 = (const float*)d_in[4];
  const float* b2 = (const float*)d_in[5];
  float* out = (float*)d_out;

  // ws: [0,4) ticket ; [256, 256+256K) M4 ; +2K biasT ; +16K partials
  int*   ticket = (int*)d_ws;
  float* M4     = (float*)((char*)d_ws + 256);
  float* biasT  = (float*)((char*)d_ws + 256 + 4 * 128 * 128 * sizeof(float));
  unsigned long long* partials =
      (unsigned long long*)((char*)d_ws + 256 + 4 * 128 * 128 * sizeof(float) + 4 * 128 * sizeof(float));

  prepK<<<517, 128, 0, stream>>>(w1, b1, w2, b2, M4, biasT, ticket);
  mainK<<<NBLK, 128, 0, stream>>>(x, y, M4, biasT, partials, ticket, out);
}